// Round 1
// 742.634 us; speedup vs baseline: 1.0950x; 1.0950x over previous
//
#include <hip/hip_runtime.h>
#include <hip/hip_bf16.h>
#include <math.h>

#define NEG 0.1f

typedef __attribute__((ext_vector_type(8))) short short8;
typedef __attribute__((ext_vector_type(4))) float f32x4;

__device__ __forceinline__ float lrelu(float x){ return x >= 0.f ? x : NEG*x; }

// fp32x2 -> packed bf16x2 (RTNE) via HIP intrinsic (lowers to v_cvt_pk_bf16_f32 on gfx950)
__device__ __forceinline__ unsigned pk2(float lo, float hi){
    __hip_bfloat162 h = __float22bfloat162_rn(make_float2(lo, hi));
    union { __hip_bfloat162 h2; unsigned u; } cv; cv.h2 = h;
    return cv.u;
}
__device__ __forceinline__ float bflo(unsigned u){ return __uint_as_float(u << 16); }
__device__ __forceinline__ float bfhi(unsigned u){ return __uint_as_float(u & 0xFFFF0000u); }

// RTNE bf16 round of fp32, returned as fp32-bit-pattern (low 16 zero)
__device__ __forceinline__ unsigned bfrnd(float f){
    unsigned u = __float_as_uint(f);
    return (u + 0x7FFFu + ((u >> 16) & 1u)) & 0xFFFF0000u;
}

// ---- prepass: w_in (512x256 fp32) -> bf16 row-major ----
__global__ __launch_bounds__(256) void k_wprep(const float* __restrict__ w_in, unsigned* __restrict__ wbf_u){
    int idx8 = (blockIdx.x*256 + threadIdx.x)*8;
    float4 v0 = *(const float4*)&w_in[idx8];
    float4 v1 = *(const float4*)&w_in[idx8+4];
    uint4 d;
    d.x = pk2(v0.x, v0.y); d.y = pk2(v0.z, v0.w);
    d.z = pk2(v1.x, v1.y); d.w = pk2(v1.z, v1.w);
    *(uint4*)&wbf_u[idx8>>1] = d;
}

// ---- pool1: input1 (8,512,128,128) -> p1t bf16 (b,n,c); LDS-staged coalesced writes ----
__global__ __launch_bounds__(256) void k_pool1(const float* __restrict__ in1, unsigned* __restrict__ p1u){
    __shared__ unsigned sm[64*20];   // 64 n-rows x 16 uints, stride 20 (16B-aligned, conflict-light)
    const int y = blockIdx.x, cg = blockIdx.y, b = blockIdx.z;
    const int tid = threadIdx.x;
    const int x = tid & 63, w = tid >> 6;
    const int cbase = cg*32 + w*8;
    const float2* iv = (const float2*)in1;
    float out[8];
    #pragma unroll
    for (int j = 0; j < 8; ++j){
        int c = cbase + j;
        size_t r0 = (size_t)(b*512 + c)*8192 + (2*y)*64 + x;
        float2 a = iv[r0];
        float2 bb = iv[r0 + 64];
        float m = fmaxf(fmaxf(a.x,a.y), fmaxf(bb.x,bb.y));
        out[j] = m + (a.x+a.y+bb.x+bb.y)*0.25f;
    }
    uint4 d;
    d.x = pk2(out[0],out[1]); d.y = pk2(out[2],out[3]);
    d.z = pk2(out[4],out[5]); d.w = pk2(out[6],out[7]);
    *(uint4*)&sm[x*20 + w*4] = d;
    __syncthreads();
    const int nn = tid >> 2, uq = (tid & 3)*4;
    uint4 dd = *(const uint4*)&sm[nn*20 + uq];
    *(uint4*)&p1u[(size_t)(b*4096 + y*64 + nn)*256 + cg*16 + uq] = dd;   // 4 lanes = 64B lines
}

// ---- fused 1x1 conv + bias + 2x2 max+mean pool via bf16 MFMA -> p2t bf16 (b,n,c) ----
__global__ __launch_bounds__(256) void k_convpool(const float* __restrict__ in2, const unsigned* __restrict__ wbf_u,
                                                  const float* __restrict__ b_in, unsigned short* __restrict__ p2t){
    __shared__ unsigned As[128*33];   // K-loop stride 32; epilogue reuses as float[128][33]
    __shared__ unsigned Bs[128*32];
    const int b = blockIdx.z, o0 = blockIdx.y*128;
    const int y = blockIdx.x >> 1, xg = blockIdx.x & 1;
    const int tid = threadIdx.x;
    const int lane = tid & 63, w = tid >> 6;
    const int col = lane & 15, q = lane >> 4;

    f32x4 acc[2][8];
    #pragma unroll
    for (int mt=0; mt<2; ++mt)
        #pragma unroll
        for (int nt=0; nt<8; ++nt) acc[mt][nt] = (f32x4){0.f,0.f,0.f,0.f};

    const int a_o8 = tid >> 3;
    const int a_kg = tid & 7;
    const int b_c4 = tid & 15, b_r = (tid>>4)&1, b_kg = tid>>5;
    const int b_n = b_r*64 + b_c4*4;

    for (int kb = 0; kb < 4; ++kb){
        __syncthreads();
        // ---- stage A: bf16 copy (pre-converted), swizzled ----
        #pragma unroll
        for (int pass=0; pass<4; ++pass){
            int o = pass*32 + a_o8;
            uint4 d = *(const uint4*)&wbf_u[((size_t)(o0+o)*256 + kb*64 + a_kg*8) >> 1];
            *(uint4*)&As[o*32 + ((a_kg ^ ((o>>1)&7))<<2)] = d;
        }
        // ---- stage B: 128 pixels x 64 k, register transpose + packed cvt ----
        float r[8][4];
        #pragma unroll
        for (int kk=0; kk<8; ++kk){
            int k = kb*64 + b_kg*8 + kk;
            float4 v = *(const float4*)&in2[((size_t)(b*256 + k)*128 + 2*y + b_r)*128 + xg*64 + b_c4*4];
            r[kk][0]=v.x; r[kk][1]=v.y; r[kk][2]=v.z; r[kk][3]=v.w;
        }
        #pragma unroll
        for (int i=0; i<4; ++i){
            int n = b_n + i;
            uint4 d;
            d.x = pk2(r[0][i], r[1][i]); d.y = pk2(r[2][i], r[3][i]);
            d.z = pk2(r[4][i], r[5][i]); d.w = pk2(r[6][i], r[7][i]);
            *(uint4*)&Bs[n*32 + ((b_kg ^ ((n>>1)&7))<<2)] = d;
        }
        __syncthreads();
        #pragma unroll
        for (int ks=0; ks<2; ++ks){
            int g = ks*4 + q;
            short8 af[2], bf[8];
            #pragma unroll
            for (int mt=0; mt<2; ++mt){
                int m = w*32 + mt*16 + col;
                af[mt] = *(const short8*)&As[m*32 + ((g ^ ((m>>1)&7))<<2)];
            }
            #pragma unroll
            for (int nt=0; nt<8; ++nt){
                int n = nt*16 + col;
                bf[nt] = *(const short8*)&Bs[n*32 + ((g ^ ((n>>1)&7))<<2)];
            }
            #pragma unroll
            for (int mt=0; mt<2; ++mt)
                #pragma unroll
                for (int nt=0; nt<8; ++nt)
                    acc[mt][nt] = __builtin_amdgcn_mfma_f32_16x16x32_bf16(af[mt], bf[nt], acc[mt][nt], 0,0,0);
        }
    }
    __syncthreads();
    float* outs = (float*)As;   // stride 33
    #pragma unroll
    for (int mt=0; mt<2; ++mt){
        #pragma unroll
        for (int nt=0; nt<4; ++nt){
            #pragma unroll
            for (int reg=0; reg<4; ++reg){
                float a = acc[mt][nt][reg], bb = acc[mt][nt+4][reg];
                float mx = fmaxf(a, bb), sm = a + bb;
                float mx2 = fmaxf(mx, __shfl_xor(mx, 1));
                float sm2 = sm + __shfl_xor(sm, 1);
                if ((lane & 1) == 0){
                    int p = nt*8 + (col>>1);
                    int o = w*32 + mt*16 + q*4 + reg;
                    outs[o*33 + p] = mx2 + sm2*0.25f;
                }
            }
        }
    }
    __syncthreads();
    const int o4 = tid & 31, pp = tid >> 5;
    #pragma unroll
    for (int pass=0; pass<4; ++pass){
        int p = pass*8 + pp;
        int n = y*64 + xg*32 + p;
        float v0 = outs[(o4*4+0)*33 + p] + 2.0f*b_in[o0+o4*4+0];
        float v1 = outs[(o4*4+1)*33 + p] + 2.0f*b_in[o0+o4*4+1];
        float v2 = outs[(o4*4+2)*33 + p] + 2.0f*b_in[o0+o4*4+2];
        float v3 = outs[(o4*4+3)*33 + p] + 2.0f*b_in[o0+o4*4+3];
        uint2 d; d.x = pk2(v0,v1); d.y = pk2(v2,v3);
        *(uint2*)&p2t[(size_t)(b*4096 + n)*512 + o0 + o4*4] = d;
    }
}

// ---- rows: q=focus(lrelu(p1+pos1)/spl) in-place bf16; k likewise -> kfoc. 2 rows/block ----
__global__ __launch_bounds__(256) void k_rows(unsigned* __restrict__ p1u, const unsigned* __restrict__ p2u,
                                              const float* __restrict__ pos1, const float* __restrict__ pos2,
                                              const float* __restrict__ scale_param, unsigned* __restrict__ kfu){
    const int b = blockIdx.y;
    const int tid = threadIdx.x;
    const int half = tid >> 7, t = tid & 127;
    const int n = blockIdx.x*2 + half;
    const int c0 = t*4;
    const size_t base2 = (size_t)(b*4096 + n)*128;   // uint2 index
    __shared__ float red[4][4];
    uint2 u1 = *(const uint2*)&p1u[base2*2 + t*2];
    uint2 u2 = *(const uint2*)&p2u[base2*2 + t*2];
    float4 po1 = *(const float4*)&pos1[n*512 + c0];
    float4 po2 = *(const float4*)&pos2[n*512 + c0];
    float4 scv = *(const float4*)&scale_param[c0];
    float qv[4], kv_[4];
    float pq2=0.f, pq6=0.f, pk2_=0.f, pk6=0.f;
    {
        float p1a[4] = {bflo(u1.x), bfhi(u1.x), bflo(u1.y), bfhi(u1.y)};
        float p2a[4] = {bflo(u2.x), bfhi(u2.x), bflo(u2.y), bfhi(u2.y)};
        float poa1[4] = {po1.x,po1.y,po1.z,po1.w};
        float poa2[4] = {po2.x,po2.y,po2.z,po2.w};
        float sca[4] = {scv.x,scv.y,scv.z,scv.w};
        #pragma unroll
        for (int j = 0; j < 4; ++j){
            float sp = sca[j];
            float inv = 1.0f/(fmaxf(sp,0.f) + log1pf(expf(-fabsf(sp))));
            float qq = lrelu(p1a[j] + poa1[j]) * inv;
            float kk = lrelu(p2a[j] + poa2[j]) * inv;
            qv[j]=qq; kv_[j]=kk;
            float a;
            a = qq*qq; pq2 += a; pq6 += a*a*a;
            a = kk*kk; pk2_ += a; pk6 += a*a*a;
        }
    }
    #pragma unroll
    for (int off = 32; off > 0; off >>= 1){
        pq2 += __shfl_xor(pq2, off);
        pq6 += __shfl_xor(pq6, off);
        pk2_ += __shfl_xor(pk2_, off);
        pk6 += __shfl_xor(pk6, off);
    }
    int wave = tid >> 6;
    if ((tid & 63) == 0){ red[wave][0]=pq2; red[wave][1]=pq6; red[wave][2]=pk2_; red[wave][3]=pk6; }
    __syncthreads();
    float sq2 = red[2*half][0]+red[2*half+1][0];
    float sq6 = red[2*half][1]+red[2*half+1][1];
    float sk2 = red[2*half][2]+red[2*half+1][2];
    float sk6 = red[2*half][3]+red[2*half+1][3];
    float fq = sqrtf(sq2/sq6);
    float fk = sqrtf(sk2/sk6);
    uint2 dq, dk;
    dq.x = pk2(qv[0]*qv[0]*qv[0]*fq, qv[1]*qv[1]*qv[1]*fq);
    dq.y = pk2(qv[2]*qv[2]*qv[2]*fq, qv[3]*qv[3]*qv[3]*fq);
    dk.x = pk2(kv_[0]*kv_[0]*kv_[0]*fk, kv_[1]*kv_[1]*kv_[1]*fk);
    dk.y = pk2(kv_[2]*kv_[2]*kv_[2]*fk, kv_[3]*kv_[3]*kv_[3]*fk);
    *(uint2*)&p1u[base2*2 + t*2] = dq;
    *(uint2*)&kfu[base2*2 + t*2] = dk;
}

// ---- kv[b,h,d,e] = sum_n k*v / N ; 4x4 outputs/thread, wave-per-n-subset, LDS reduce ----
// grid (4 nc, 16 h, 8 b); each block covers 1024 n in 4 chunks of 256.
__global__ __launch_bounds__(256) void k_kv(const unsigned* __restrict__ kfu, const unsigned* __restrict__ p2u,
                                            float* __restrict__ kv){
    __shared__ unsigned ksu[4096], vsu[4096];
    __shared__ float part[4][32*36];
    const int nc = blockIdx.x, h = blockIdx.y, b = blockIdx.z;
    const int tid = threadIdx.x;
    const int wave = tid >> 6, lane = tid & 63;
    const int d0 = (lane >> 3)*4, e0 = (lane & 7)*4;
    float acc[4][4];
    #pragma unroll
    for (int di=0; di<4; ++di)
        #pragma unroll
        for (int ej=0; ej<4; ++ej) acc[di][ej] = 0.f;

    for (int ch = 0; ch < 4; ++ch){
        __syncthreads();
        #pragma unroll
        for (int it = 0; it < 16; ++it){
            int i = it*256 + tid;
            int n = i >> 4, u = i & 15;
            size_t g = (size_t)(b*4096 + nc*1024 + ch*256 + n)*256 + h*16 + u;
            ksu[i] = kfu[g];
            vsu[i] = p2u[g];
        }
        __syncthreads();
        #pragma unroll 4
        for (int i = 0; i < 64; ++i){
            int n = i*4 + wave;
            uint2 ku = *(const uint2*)&ksu[n*16 + (d0>>1)];
            uint2 vu = *(const uint2*)&vsu[n*16 + (e0>>1)];
            float kd[4] = {bflo(ku.x), bfhi(ku.x), bflo(ku.y), bfhi(ku.y)};
            float ve[4] = {bflo(vu.x), bfhi(vu.x), bflo(vu.y), bfhi(vu.y)};
            #pragma unroll
            for (int di=0; di<4; ++di)
                #pragma unroll
                for (int ej=0; ej<4; ++ej)
                    acc[di][ej] += kd[di]*ve[ej];
        }
    }
    // cross-wave reduce: each wave holds the full 32x32 grid for its n-subset
    float* pw = &part[wave][0];
    #pragma unroll
    for (int di=0; di<4; ++di)
        *(float4*)&pw[(d0+di)*36 + e0] = make_float4(acc[di][0], acc[di][1], acc[di][2], acc[di][3]);
    __syncthreads();
    const int d = tid >> 3, ef = (tid & 7)*4;
    float4 s0 = *(const float4*)&part[0][d*36 + ef];
    float4 s1 = *(const float4*)&part[1][d*36 + ef];
    float4 s2 = *(const float4*)&part[2][d*36 + ef];
    float4 s3 = *(const float4*)&part[3][d*36 + ef];
    const float sc = 1.0f/4096.0f;
    float* dst = &kv[((size_t)(b*16 + h)*32 + d)*32 + ef];
    atomicAdd(dst+0, (s0.x+s1.x+s2.x+s3.x)*sc);
    atomicAdd(dst+1, (s0.y+s1.y+s2.y+s3.y)*sc);
    atomicAdd(dst+2, (s0.z+s1.z+s2.z+s3.z)*sc);
    atomicAdd(dst+3, (s0.w+s1.w+s2.w+s3.w)*sc);
}

// ---- attn: x = q.kv + lrelu(v.w_v^T + b_v) via MFMA (hi/lo bf16 split of kv & w_v) ----
// output (b,c,n) bf16. Per block: 64 n x 32 e; 4 waves each own one 16-row n-tile.
__global__ __launch_bounds__(256) void k_attn(const unsigned* __restrict__ qfu, const unsigned* __restrict__ p2u,
                                              const float* __restrict__ kv, const float* __restrict__ w_v,
                                              const float* __restrict__ b_v, unsigned short* __restrict__ attn){
    __shared__ unsigned short qs[64*40];            // A-tile q: row n, 32 d contiguous (stride 40)
    __shared__ unsigned short vs[64*40];            // A-tile v
    __shared__ unsigned short kvh[32*40], kvl[32*40];   // B-tile kv^T hi/lo: row e, 32 d
    __shared__ unsigned short wvh[32*40], wvl[32*40];   // B-tile w_v hi/lo: row e, 32 d
    __shared__ float to[32*68];                     // out transpose buffer [e][n]
    const int nt = blockIdx.x, h = blockIdx.y, b = blockIdx.z;
    const int tid = threadIdx.x;
    // ---- stage q,v tiles: 64 rows x 16 uints ----
    {
        const int nn = tid >> 2, up = (tid & 3)*4;
        size_t g = (size_t)(b*4096 + nt*64 + nn)*256 + h*16 + up;
        uint4 qu = *(const uint4*)&qfu[g];
        uint4 vu = *(const uint4*)&p2u[g];
        *(uint4*)&qs[nn*40 + up*2] = qu;
        *(uint4*)&vs[nn*40 + up*2] = vu;
    }
    // ---- stage kv^T hi/lo (transpose read from fp32, L2-hot 4KB) + w_v hi/lo ----
    {
        const int e = tid >> 3, d0 = (tid & 7)*4;
        const float* kvp = &kv[(size_t)(b*16 + h)*1024];
        unsigned hb[4]; float lo[4];
        #pragma unroll
        for (int i=0; i<4; ++i){
            float f = kvp[(d0+i)*32 + e];
            hb[i] = bfrnd(f);
            lo[i] = f - __uint_as_float(hb[i]);
        }
        uint2 dh, dl;
        dh.x = (hb[0]>>16) | hb[1]; dh.y = (hb[2]>>16) | hb[3];
        dl.x = pk2(lo[0], lo[1]);   dl.y = pk2(lo[2], lo[3]);
        *(uint2*)&kvh[e*40 + d0] = dh;
        *(uint2*)&kvl[e*40 + d0] = dl;
        float4 wf = *(const float4*)&w_v[e*32 + d0];
        float wfa[4] = {wf.x, wf.y, wf.z, wf.w};
        #pragma unroll
        for (int i=0; i<4; ++i){
            hb[i] = bfrnd(wfa[i]);
            lo[i] = wfa[i] - __uint_as_float(hb[i]);
        }
        dh.x = (hb[0]>>16) | hb[1]; dh.y = (hb[2]>>16) | hb[3];
        dl.x = pk2(lo[0], lo[1]);   dl.y = pk2(lo[2], lo[3]);
        *(uint2*)&wvh[e*40 + d0] = dh;
        *(uint2*)&wvl[e*40 + d0] = dl;
    }
    __syncthreads();
    const int lane = tid & 63, w = tid >> 6;
    const int col = lane & 15, q8 = lane >> 4;
    short8 aq = *(const short8*)&qs[(w*16 + col)*40 + q8*8];
    short8 av = *(const short8*)&vs[(w*16 + col)*40 + q8*8];
    f32x4 ax[2], avc[2];
    #pragma unroll
    for (int et=0; et<2; ++et){ ax[et] = (f32x4){0.f,0.f,0.f,0.f}; avc[et] = (f32x4){0.f,0.f,0.f,0.f}; }
    #pragma unroll
    for (int et=0; et<2; ++et){
        short8 bh = *(const short8*)&kvh[(et*16 + col)*40 + q8*8];
        short8 bl = *(const short8*)&kvl[(et*16 + col)*40 + q8*8];
        ax[et] = __builtin_amdgcn_mfma_f32_16x16x32_bf16(aq, bh, ax[et], 0,0,0);
        ax[et] = __builtin_amdgcn_mfma_f32_16x16x32_bf16(aq, bl, ax[et], 0,0,0);
        short8 wh = *(const short8*)&wvh[(et*16 + col)*40 + q8*8];
        short8 wl = *(const short8*)&wvl[(et*16 + col)*40 + q8*8];
        avc[et] = __builtin_amdgcn_mfma_f32_16x16x32_bf16(av, wh, avc[et], 0,0,0);
        avc[et] = __builtin_amdgcn_mfma_f32_16x16x32_bf16(av, wl, avc[et], 0,0,0);
    }
    // epilogue: to[e][n] = x + lrelu(vc + b_v[e]); D layout: col=lane&15, row=q8*4+reg
    #pragma unroll
    for (int et=0; et<2; ++et){
        int e = et*16 + col;
        float bve = b_v[e];
        float4 o;
        o.x = ax[et][0] + lrelu(avc[et][0] + bve);
        o.y = ax[et][1] + lrelu(avc[et][1] + bve);
        o.z = ax[et][2] + lrelu(avc[et][2] + bve);
        o.w = ax[et][3] + lrelu(avc[et][3] + bve);
        *(float4*)&to[e*68 + w*16 + q8*4] = o;
    }
    __syncthreads();
    const int cc = tid >> 3, n8 = (tid & 7)*8;
    float4 t0 = *(const float4*)&to[cc*68 + n8];
    float4 t1 = *(const float4*)&to[cc*68 + n8 + 4];
    uint4 d;
    d.x = pk2(t0.x,t0.y); d.y = pk2(t0.z,t0.w);
    d.z = pk2(t1.x,t1.y); d.w = pk2(t1.z,t1.w);
    *(uint4*)&attn[((size_t)(b*512) + h*32 + cc)*4096 + nt*64 + n8] = d;
}

// ---- bilinear 64->128 align_corners + sigmoid; attn bf16 (b,c,n) -> out fp32 ----
__global__ __launch_bounds__(256) void k_up(const unsigned* __restrict__ attn_u, float* __restrict__ out){
    __shared__ float sA[18*65];
    const int qy = blockIdx.x;            // 0..3
    const int bc = blockIdx.y;            // 0..4095
    const int tid = threadIdx.x;
    const int ybase = (qy*32*63)/127;     // 0,15,31,47
    const size_t sb = (size_t)bc*2048;    // uints per bc slice
    for (int i = tid; i < 576; i += 256){
        int r = i >> 5, cu = i & 31;
        int ridx = ybase + r; if (ridx > 63) ridx = 63;
        unsigned u = attn_u[sb + ridx*32 + cu];
        sA[r*65 + cu*2]   = bflo(u);
        sA[r*65 + cu*2+1] = bfhi(u);
    }
    __syncthreads();
    const float rr = 63.0f/127.0f;
    const int ro = tid >> 3, cbase = tid & 7;
    const int yo = qy*32 + ro;
    float ty = yo * rr;
    int y0 = (int)ty; y0 = y0 > 62 ? 62 : y0;
    float wy = ty - (float)y0;
    const float* ra = &sA[(y0 - ybase)*65];
    const float* rb = ra + 65;
    float* orow = &out[((size_t)bc*128 + yo)*128];
    #pragma unroll
    for (int t = 0; t < 4; ++t){
        int xo0 = (cbase + t*8)*4;
        float4 o;
        float* op = (float*)&o;
        #pragma unroll
        for (int j = 0; j < 4; ++j){
            int xo = xo0 + j;
            float tx = xo * rr;
            int x0 = (int)tx; x0 = x0 > 62 ? 62 : x0;
            float wx = tx - (float)x0;
            float a00 = ra[x0], a01 = ra[x0+1];
            float a10 = rb[x0], a11 = rb[x0+1];
            float v = (a00*(1.f-wy) + a10*wy)*(1.f-wx) + (a01*(1.f-wy) + a11*wy)*wx;
            op[j] = 1.0f/(1.0f + expf(-v));
        }
        *(float4*)&orow[xo0] = o;
    }
}

extern "C" void kernel_launch(void* const* d_in, const int* in_sizes, int n_in,
                              void* d_out, int out_size, void* d_ws, size_t ws_size,
                              hipStream_t stream){
    const float* in1  = (const float*)d_in[0];
    const float* in2  = (const float*)d_in[1];
    const float* w_in = (const float*)d_in[2];
    const float* b_in = (const float*)d_in[3];
    const float* w_v  = (const float*)d_in[4];
    const float* b_v  = (const float*)d_in[5];
    const float* scp  = (const float*)d_in[6];
    const float* pos1 = (const float*)d_in[7];
    const float* pos2 = (const float*)d_in[8];
    float* out = (float*)d_out;
    char* ws  = (char*)d_ws;

    const size_t PBYTES = (size_t)8*4096*512*2;   // 33.55 MB per bf16 (b,n,c) buffer
    unsigned short* p1t  = (unsigned short*)ws;                 // qfoc in-place after k_rows
    unsigned short* p2t  = (unsigned short*)(ws + PBYTES);      // pooled projected input2 == v
    unsigned short* kfoc = (unsigned short*)(ws + 2*PBYTES);    // focused k; reused as attn (b,c,n)
    float*          kvb  = (float*)(ws + 3*PBYTES);             // 512 KB
    unsigned*       wbf  = (unsigned*)(ws + 3*PBYTES + (size_t)8*16*32*32*4);  // 256 KB bf16 w_in

    hipMemsetAsync(kvb, 0, (size_t)8*16*32*32*sizeof(float), stream);
    k_wprep   <<<64,            256, 0, stream>>>(w_in, wbf);
    k_pool1   <<<dim3(64,16,8), 256, 0, stream>>>(in1, (unsigned*)p1t);
    k_convpool<<<dim3(128,4,8), 256, 0, stream>>>(in2, wbf, b_in, p2t);
    k_rows    <<<dim3(2048,8),  256, 0, stream>>>((unsigned*)p1t, (const unsigned*)p2t, pos1, pos2, scp, (unsigned*)kfoc);
    k_kv      <<<dim3(4,16,8),  256, 0, stream>>>((const unsigned*)kfoc, (const unsigned*)p2t, kvb);
    k_attn    <<<dim3(64,16,8), 256, 0, stream>>>((const unsigned*)p1t, (const unsigned*)p2t, kvb, w_v, b_v, kfoc);
    k_up      <<<dim3(4,4096),  256, 0, stream>>>((const unsigned*)kfoc, out);
}

// Round 2
// 704.892 us; speedup vs baseline: 1.1537x; 1.0535x over previous
//
#include <hip/hip_runtime.h>
#include <hip/hip_bf16.h>
#include <math.h>

#define NEG 0.1f

typedef __attribute__((ext_vector_type(8))) short short8;
typedef __attribute__((ext_vector_type(4))) float f32x4;

__device__ __forceinline__ float lrelu(float x){ return x >= 0.f ? x : NEG*x; }

// fp32x2 -> packed bf16x2 (RTNE) via HIP intrinsic (lowers to v_cvt_pk_bf16_f32 on gfx950)
__device__ __forceinline__ unsigned pk2(float lo, float hi){
    __hip_bfloat162 h = __float22bfloat162_rn(make_float2(lo, hi));
    union { __hip_bfloat162 h2; unsigned u; } cv; cv.h2 = h;
    return cv.u;
}
__device__ __forceinline__ float bflo(unsigned u){ return __uint_as_float(u << 16); }
__device__ __forceinline__ float bfhi(unsigned u){ return __uint_as_float(u & 0xFFFF0000u); }

// RTNE bf16 round of fp32, returned as fp32-bit-pattern (low 16 zero)
__device__ __forceinline__ unsigned bfrnd(float f){
    unsigned u = __float_as_uint(f);
    return (u + 0x7FFFu + ((u >> 16) & 1u)) & 0xFFFF0000u;
}

// ---- prepass: w_in (512x256 fp32) -> bf16 row-major ----
__global__ __launch_bounds__(256) void k_wprep(const float* __restrict__ w_in, unsigned* __restrict__ wbf_u){
    int idx8 = (blockIdx.x*256 + threadIdx.x)*8;
    float4 v0 = *(const float4*)&w_in[idx8];
    float4 v1 = *(const float4*)&w_in[idx8+4];
    uint4 d;
    d.x = pk2(v0.x, v0.y); d.y = pk2(v0.z, v0.w);
    d.z = pk2(v1.x, v1.y); d.w = pk2(v1.z, v1.w);
    *(uint4*)&wbf_u[idx8>>1] = d;
}

// ---- stage1: pool1 (BW-bound) + convpool (MFMA-bound) merged, 1:2 interleaved ----
// bid%3==2 -> convpool block (4096 total); else pool1 block (8192 total).
// Overlap: pool1 streaming loads hide under convpool MFMA phases on the same CU.
__global__ __launch_bounds__(256) void k_stage1(const float* __restrict__ in1, const float* __restrict__ in2,
                                                const unsigned* __restrict__ wbf_u, const float* __restrict__ b_in,
                                                unsigned* __restrict__ p1u, unsigned short* __restrict__ p2t){
    __shared__ unsigned As[128*33];   // conv: A-tile / epilogue floats; pool1: staging (first 1280)
    __shared__ unsigned Bs[128*32];
    const int bid = blockIdx.x;
    const int t3 = bid / 3, r3 = bid - t3*3;
    const int tid = threadIdx.x;

    if (r3 != 2){
        // ================= pool1 =================
        const int pid = 2*t3 + r3;            // 0..8191
        const int y = pid & 63, cg = (pid >> 6) & 15, b = pid >> 10;
        const int x = tid & 63, w = tid >> 6;
        const int cbase = cg*32 + w*8;
        const float2* iv = (const float2*)in1;
        float out[8];
        #pragma unroll
        for (int j = 0; j < 8; ++j){
            int c = cbase + j;
            size_t r0 = (size_t)(b*512 + c)*8192 + (2*y)*64 + x;
            float2 a = iv[r0];
            float2 bb = iv[r0 + 64];
            float m = fmaxf(fmaxf(a.x,a.y), fmaxf(bb.x,bb.y));
            out[j] = m + (a.x+a.y+bb.x+bb.y)*0.25f;
        }
        uint4 d;
        d.x = pk2(out[0],out[1]); d.y = pk2(out[2],out[3]);
        d.z = pk2(out[4],out[5]); d.w = pk2(out[6],out[7]);
        *(uint4*)&As[x*20 + w*4] = d;
        __syncthreads();
        const int nn = tid >> 2, uq = (tid & 3)*4;
        uint4 dd = *(const uint4*)&As[nn*20 + uq];
        *(uint4*)&p1u[(size_t)(b*4096 + y*64 + nn)*256 + cg*16 + uq] = dd;
        return;
    }

    // ================= convpool =================
    const int cid = t3;                       // 0..4095
    const int bx = cid & 127, og = (cid >> 7) & 3, b = cid >> 9;
    const int o0 = og*128;
    const int y = bx >> 1, xg = bx & 1;
    const int lane = tid & 63, w = tid >> 6;
    const int col = lane & 15, q = lane >> 4;

    f32x4 acc[2][8];
    #pragma unroll
    for (int mt=0; mt<2; ++mt)
        #pragma unroll
        for (int nt=0; nt<8; ++nt) acc[mt][nt] = (f32x4){0.f,0.f,0.f,0.f};

    const int a_o8 = tid >> 3;
    const int a_kg = tid & 7;
    const int b_c4 = tid & 15, b_r = (tid>>4)&1, b_kg = tid>>5;
    const int b_n = b_r*64 + b_c4*4;

    for (int kb = 0; kb < 4; ++kb){
        __syncthreads();
        // ---- stage A: bf16 copy (pre-converted), swizzled ----
        #pragma unroll
        for (int pass=0; pass<4; ++pass){
            int o = pass*32 + a_o8;
            uint4 d = *(const uint4*)&wbf_u[((size_t)(o0+o)*256 + kb*64 + a_kg*8) >> 1];
            *(uint4*)&As[o*32 + ((a_kg ^ ((o>>1)&7))<<2)] = d;
        }
        // ---- stage B: 128 pixels x 64 k, register transpose + packed cvt ----
        float r[8][4];
        #pragma unroll
        for (int kk=0; kk<8; ++kk){
            int k = kb*64 + b_kg*8 + kk;
            float4 v = *(const float4*)&in2[((size_t)(b*256 + k)*128 + 2*y + b_r)*128 + xg*64 + b_c4*4];
            r[kk][0]=v.x; r[kk][1]=v.y; r[kk][2]=v.z; r[kk][3]=v.w;
        }
        #pragma unroll
        for (int i=0; i<4; ++i){
            int n = b_n + i;
            uint4 d;
            d.x = pk2(r[0][i], r[1][i]); d.y = pk2(r[2][i], r[3][i]);
            d.z = pk2(r[4][i], r[5][i]); d.w = pk2(r[6][i], r[7][i]);
            *(uint4*)&Bs[n*32 + ((b_kg ^ ((n>>1)&7))<<2)] = d;
        }
        __syncthreads();
        #pragma unroll
        for (int ks=0; ks<2; ++ks){
            int g = ks*4 + q;
            short8 af[2], bf[8];
            #pragma unroll
            for (int mt=0; mt<2; ++mt){
                int m = w*32 + mt*16 + col;
                af[mt] = *(const short8*)&As[m*32 + ((g ^ ((m>>1)&7))<<2)];
            }
            #pragma unroll
            for (int nt=0; nt<8; ++nt){
                int n = nt*16 + col;
                bf[nt] = *(const short8*)&Bs[n*32 + ((g ^ ((n>>1)&7))<<2)];
            }
            #pragma unroll
            for (int mt=0; mt<2; ++mt)
                #pragma unroll
                for (int nt=0; nt<8; ++nt)
                    acc[mt][nt] = __builtin_amdgcn_mfma_f32_16x16x32_bf16(af[mt], bf[nt], acc[mt][nt], 0,0,0);
        }
    }
    __syncthreads();
    float* outs = (float*)As;   // stride 33
    #pragma unroll
    for (int mt=0; mt<2; ++mt){
        #pragma unroll
        for (int nt=0; nt<4; ++nt){
            #pragma unroll
            for (int reg=0; reg<4; ++reg){
                float a = acc[mt][nt][reg], bb = acc[mt][nt+4][reg];
                float mx = fmaxf(a, bb), sm = a + bb;
                float mx2 = fmaxf(mx, __shfl_xor(mx, 1));
                float sm2 = sm + __shfl_xor(sm, 1);
                if ((lane & 1) == 0){
                    int p = nt*8 + (col>>1);
                    int o = w*32 + mt*16 + q*4 + reg;
                    outs[o*33 + p] = mx2 + sm2*0.25f;
                }
            }
        }
    }
    __syncthreads();
    const int o4 = tid & 31, pp = tid >> 5;
    #pragma unroll
    for (int pass=0; pass<4; ++pass){
        int p = pass*8 + pp;
        int n = y*64 + xg*32 + p;
        float v0 = outs[(o4*4+0)*33 + p] + 2.0f*b_in[o0+o4*4+0];
        float v1 = outs[(o4*4+1)*33 + p] + 2.0f*b_in[o0+o4*4+1];
        float v2 = outs[(o4*4+2)*33 + p] + 2.0f*b_in[o0+o4*4+2];
        float v3 = outs[(o4*4+3)*33 + p] + 2.0f*b_in[o0+o4*4+3];
        uint2 d; d.x = pk2(v0,v1); d.y = pk2(v2,v3);
        *(uint2*)&p2t[(size_t)(b*4096 + n)*512 + o0 + o4*4] = d;
    }
}

// ---- rows: q=focus(lrelu(p1+pos1)/spl) in-place bf16; k likewise -> kfoc. 2 rows/block ----
__global__ __launch_bounds__(256) void k_rows(unsigned* __restrict__ p1u, const unsigned* __restrict__ p2u,
                                              const float* __restrict__ pos1, const float* __restrict__ pos2,
                                              const float* __restrict__ scale_param, unsigned* __restrict__ kfu){
    const int b = blockIdx.y;
    const int tid = threadIdx.x;
    const int half = tid >> 7, t = tid & 127;
    const int n = blockIdx.x*2 + half;
    const int c0 = t*4;
    const size_t base2 = (size_t)(b*4096 + n)*128;   // uint2 index
    __shared__ float red[4][4];
    uint2 u1 = *(const uint2*)&p1u[base2*2 + t*2];
    uint2 u2 = *(const uint2*)&p2u[base2*2 + t*2];
    float4 po1 = *(const float4*)&pos1[n*512 + c0];
    float4 po2 = *(const float4*)&pos2[n*512 + c0];
    float4 scv = *(const float4*)&scale_param[c0];
    float qv[4], kv_[4];
    float pq2=0.f, pq6=0.f, pk2_=0.f, pk6=0.f;
    {
        float p1a[4] = {bflo(u1.x), bfhi(u1.x), bflo(u1.y), bfhi(u1.y)};
        float p2a[4] = {bflo(u2.x), bfhi(u2.x), bflo(u2.y), bfhi(u2.y)};
        float poa1[4] = {po1.x,po1.y,po1.z,po1.w};
        float poa2[4] = {po2.x,po2.y,po2.z,po2.w};
        float sca[4] = {scv.x,scv.y,scv.z,scv.w};
        #pragma unroll
        for (int j = 0; j < 4; ++j){
            float sp = sca[j];
            float inv = 1.0f/(fmaxf(sp,0.f) + log1pf(expf(-fabsf(sp))));
            float qq = lrelu(p1a[j] + poa1[j]) * inv;
            float kk = lrelu(p2a[j] + poa2[j]) * inv;
            qv[j]=qq; kv_[j]=kk;
            float a;
            a = qq*qq; pq2 += a; pq6 += a*a*a;
            a = kk*kk; pk2_ += a; pk6 += a*a*a;
        }
    }
    #pragma unroll
    for (int off = 32; off > 0; off >>= 1){
        pq2 += __shfl_xor(pq2, off);
        pq6 += __shfl_xor(pq6, off);
        pk2_ += __shfl_xor(pk2_, off);
        pk6 += __shfl_xor(pk6, off);
    }
    int wave = tid >> 6;
    if ((tid & 63) == 0){ red[wave][0]=pq2; red[wave][1]=pq6; red[wave][2]=pk2_; red[wave][3]=pk6; }
    __syncthreads();
    float sq2 = red[2*half][0]+red[2*half+1][0];
    float sq6 = red[2*half][1]+red[2*half+1][1];
    float sk2 = red[2*half][2]+red[2*half+1][2];
    float sk6 = red[2*half][3]+red[2*half+1][3];
    float fq = sqrtf(sq2/sq6);
    float fk = sqrtf(sk2/sk6);
    uint2 dq, dk;
    dq.x = pk2(qv[0]*qv[0]*qv[0]*fq, qv[1]*qv[1]*qv[1]*fq);
    dq.y = pk2(qv[2]*qv[2]*qv[2]*fq, qv[3]*qv[3]*qv[3]*fq);
    dk.x = pk2(kv_[0]*kv_[0]*kv_[0]*fk, kv_[1]*kv_[1]*kv_[1]*fk);
    dk.y = pk2(kv_[2]*kv_[2]*kv_[2]*fk, kv_[3]*kv_[3]*kv_[3]*fk);
    *(uint2*)&p1u[base2*2 + t*2] = dq;
    *(uint2*)&kfu[base2*2 + t*2] = dk;
}

// ---- kv[b,h,d,e] = sum_n k*v / N ; 4x4 outputs/thread, wave-per-n-subset, LDS reduce ----
// grid (8 nc, 16 h, 8 b); each block covers 512 n in 2 chunks of 256.
__global__ __launch_bounds__(256) void k_kv(const unsigned* __restrict__ kfu, const unsigned* __restrict__ p2u,
                                            float* __restrict__ kv){
    __shared__ unsigned ksu[4096], vsu[4096];
    __shared__ float part[4][32*36];
    const int nc = blockIdx.x, h = blockIdx.y, b = blockIdx.z;
    const int tid = threadIdx.x;
    const int wave = tid >> 6, lane = tid & 63;
    const int d0 = (lane >> 3)*4, e0 = (lane & 7)*4;
    float acc[4][4];
    #pragma unroll
    for (int di=0; di<4; ++di)
        #pragma unroll
        for (int ej=0; ej<4; ++ej) acc[di][ej] = 0.f;

    for (int ch = 0; ch < 2; ++ch){
        __syncthreads();
        #pragma unroll
        for (int it = 0; it < 16; ++it){
            int i = it*256 + tid;
            int n = i >> 4, u = i & 15;
            size_t g = (size_t)(b*4096 + nc*512 + ch*256 + n)*256 + h*16 + u;
            ksu[i] = kfu[g];
            vsu[i] = p2u[g];
        }
        __syncthreads();
        #pragma unroll 4
        for (int i = 0; i < 64; ++i){
            int n = i*4 + wave;
            uint2 ku = *(const uint2*)&ksu[n*16 + (d0>>1)];
            uint2 vu = *(const uint2*)&vsu[n*16 + (e0>>1)];
            float kd[4] = {bflo(ku.x), bfhi(ku.x), bflo(ku.y), bfhi(ku.y)};
            float ve[4] = {bflo(vu.x), bfhi(vu.x), bflo(vu.y), bfhi(vu.y)};
            #pragma unroll
            for (int di=0; di<4; ++di)
                #pragma unroll
                for (int ej=0; ej<4; ++ej)
                    acc[di][ej] += kd[di]*ve[ej];
        }
    }
    // cross-wave reduce: each wave holds the full 32x32 grid for its n-subset
    float* pw = &part[wave][0];
    #pragma unroll
    for (int di=0; di<4; ++di)
        *(float4*)&pw[(d0+di)*36 + e0] = make_float4(acc[di][0], acc[di][1], acc[di][2], acc[di][3]);
    __syncthreads();
    const int d = tid >> 3, ef = (tid & 7)*4;
    float4 s0 = *(const float4*)&part[0][d*36 + ef];
    float4 s1 = *(const float4*)&part[1][d*36 + ef];
    float4 s2 = *(const float4*)&part[2][d*36 + ef];
    float4 s3 = *(const float4*)&part[3][d*36 + ef];
    const float sc = 1.0f/4096.0f;
    float* dst = &kv[((size_t)(b*16 + h)*32 + d)*32 + ef];
    atomicAdd(dst+0, (s0.x+s1.x+s2.x+s3.x)*sc);
    atomicAdd(dst+1, (s0.y+s1.y+s2.y+s3.y)*sc);
    atomicAdd(dst+2, (s0.z+s1.z+s2.z+s3.z)*sc);
    atomicAdd(dst+3, (s0.w+s1.w+s2.w+s3.w)*sc);
}

// ---- attn: x = q.kv + lrelu(v.w_v^T + b_v) via MFMA (hi/lo bf16 split of kv & w_v) ----
// output (b,c,n) bf16. Per block: 64 n x 32 e; 4 waves each own one 16-row n-tile.
__global__ __launch_bounds__(256) void k_attn(const unsigned* __restrict__ qfu, const unsigned* __restrict__ p2u,
                                              const float* __restrict__ kv, const float* __restrict__ w_v,
                                              const float* __restrict__ b_v, unsigned short* __restrict__ attn){
    __shared__ unsigned short qs[64*40];            // A-tile q: row n, 32 d contiguous (stride 40)
    __shared__ unsigned short vs[64*40];            // A-tile v
    __shared__ unsigned short kvh[32*40], kvl[32*40];   // B-tile kv^T hi/lo: row e, 32 d
    __shared__ unsigned short wvh[32*40], wvl[32*40];   // B-tile w_v hi/lo: row e, 32 d
    __shared__ float to[32*68];                     // out transpose buffer [e][n]
    const int nt = blockIdx.x, h = blockIdx.y, b = blockIdx.z;
    const int tid = threadIdx.x;
    // ---- stage q,v tiles: 64 rows x 16 uints ----
    {
        const int nn = tid >> 2, up = (tid & 3)*4;
        size_t g = (size_t)(b*4096 + nt*64 + nn)*256 + h*16 + up;
        uint4 qu = *(const uint4*)&qfu[g];
        uint4 vu = *(const uint4*)&p2u[g];
        *(uint4*)&qs[nn*40 + up*2] = qu;
        *(uint4*)&vs[nn*40 + up*2] = vu;
    }
    // ---- stage kv^T hi/lo (transpose read from fp32, L2-hot 4KB) + w_v hi/lo ----
    {
        const int e = tid >> 3, d0 = (tid & 7)*4;
        const float* kvp = &kv[(size_t)(b*16 + h)*1024];
        unsigned hb[4]; float lo[4];
        #pragma unroll
        for (int i=0; i<4; ++i){
            float f = kvp[(d0+i)*32 + e];
            hb[i] = bfrnd(f);
            lo[i] = f - __uint_as_float(hb[i]);
        }
        uint2 dh, dl;
        dh.x = (hb[0]>>16) | hb[1]; dh.y = (hb[2]>>16) | hb[3];
        dl.x = pk2(lo[0], lo[1]);   dl.y = pk2(lo[2], lo[3]);
        *(uint2*)&kvh[e*40 + d0] = dh;
        *(uint2*)&kvl[e*40 + d0] = dl;
        float4 wf = *(const float4*)&w_v[e*32 + d0];
        float wfa[4] = {wf.x, wf.y, wf.z, wf.w};
        #pragma unroll
        for (int i=0; i<4; ++i){
            hb[i] = bfrnd(wfa[i]);
            lo[i] = wfa[i] - __uint_as_float(hb[i]);
        }
        dh.x = (hb[0]>>16) | hb[1]; dh.y = (hb[2]>>16) | hb[3];
        dl.x = pk2(lo[0], lo[1]);   dl.y = pk2(lo[2], lo[3]);
        *(uint2*)&wvh[e*40 + d0] = dh;
        *(uint2*)&wvl[e*40 + d0] = dl;
    }
    __syncthreads();
    const int lane = tid & 63, w = tid >> 6;
    const int col = lane & 15, q8 = lane >> 4;
    short8 aq = *(const short8*)&qs[(w*16 + col)*40 + q8*8];
    short8 av = *(const short8*)&vs[(w*16 + col)*40 + q8*8];
    f32x4 ax[2], avc[2];
    #pragma unroll
    for (int et=0; et<2; ++et){ ax[et] = (f32x4){0.f,0.f,0.f,0.f}; avc[et] = (f32x4){0.f,0.f,0.f,0.f}; }
    #pragma unroll
    for (int et=0; et<2; ++et){
        short8 bh = *(const short8*)&kvh[(et*16 + col)*40 + q8*8];
        short8 bl = *(const short8*)&kvl[(et*16 + col)*40 + q8*8];
        ax[et] = __builtin_amdgcn_mfma_f32_16x16x32_bf16(aq, bh, ax[et], 0,0,0);
        ax[et] = __builtin_amdgcn_mfma_f32_16x16x32_bf16(aq, bl, ax[et], 0,0,0);
        short8 wh = *(const short8*)&wvh[(et*16 + col)*40 + q8*8];
        short8 wl = *(const short8*)&wvl[(et*16 + col)*40 + q8*8];
        avc[et] = __builtin_amdgcn_mfma_f32_16x16x32_bf16(av, wh, avc[et], 0,0,0);
        avc[et] = __builtin_amdgcn_mfma_f32_16x16x32_bf16(av, wl, avc[et], 0,0,0);
    }
    // epilogue: to[e][n] = x + lrelu(vc + b_v[e]); D layout: col=lane&15, row=q8*4+reg
    #pragma unroll
    for (int et=0; et<2; ++et){
        int e = et*16 + col;
        float bve = b_v[e];
        float4 o;
        o.x = ax[et][0] + lrelu(avc[et][0] + bve);
        o.y = ax[et][1] + lrelu(avc[et][1] + bve);
        o.z = ax[et][2] + lrelu(avc[et][2] + bve);
        o.w = ax[et][3] + lrelu(avc[et][3] + bve);
        *(float4*)&to[e*68 + w*16 + q8*4] = o;
    }
    __syncthreads();
    const int cc = tid >> 3, n8 = (tid & 7)*8;
    float4 t0 = *(const float4*)&to[cc*68 + n8];
    float4 t1 = *(const float4*)&to[cc*68 + n8 + 4];
    uint4 d;
    d.x = pk2(t0.x,t0.y); d.y = pk2(t0.z,t0.w);
    d.z = pk2(t1.x,t1.y); d.w = pk2(t1.z,t1.w);
    *(uint4*)&attn[((size_t)(b*512) + h*32 + cc)*4096 + nt*64 + n8] = d;
}

// ---- bilinear 64->128 align_corners + sigmoid; attn bf16 (b,c,n) -> out fp32 ----
__global__ __launch_bounds__(256) void k_up(const unsigned* __restrict__ attn_u, float* __restrict__ out){
    __shared__ float sA[18*65];
    const int qy = blockIdx.x;            // 0..3
    const int bc = blockIdx.y;            // 0..4095
    const int tid = threadIdx.x;
    const int ybase = (qy*32*63)/127;     // 0,15,31,47
    const size_t sb = (size_t)bc*2048;    // uints per bc slice
    for (int i = tid; i < 576; i += 256){
        int r = i >> 5, cu = i & 31;
        int ridx = ybase + r; if (ridx > 63) ridx = 63;
        unsigned u = attn_u[sb + ridx*32 + cu];
        sA[r*65 + cu*2]   = bflo(u);
        sA[r*65 + cu*2+1] = bfhi(u);
    }
    __syncthreads();
    const float rr = 63.0f/127.0f;
    const int ro = tid >> 3, cbase = tid & 7;
    const int yo = qy*32 + ro;
    float ty = yo * rr;
    int y0 = (int)ty; y0 = y0 > 62 ? 62 : y0;
    float wy = ty - (float)y0;
    const float* ra = &sA[(y0 - ybase)*65];
    const float* rb = ra + 65;
    float* orow = &out[((size_t)bc*128 + yo)*128];
    #pragma unroll
    for (int t = 0; t < 4; ++t){
        int xo0 = (cbase + t*8)*4;
        float4 o;
        float* op = (float*)&o;
        #pragma unroll
        for (int j = 0; j < 4; ++j){
            int xo = xo0 + j;
            float tx = xo * rr;
            int x0 = (int)tx; x0 = x0 > 62 ? 62 : x0;
            float wx = tx - (float)x0;
            float a00 = ra[x0], a01 = ra[x0+1];
            float a10 = rb[x0], a11 = rb[x0+1];
            float v = (a00*(1.f-wy) + a10*wy)*(1.f-wx) + (a01*(1.f-wy) + a11*wy)*wx;
            op[j] = 1.0f/(1.0f + expf(-v));
        }
        *(float4*)&orow[xo0] = o;
    }
}

extern "C" void kernel_launch(void* const* d_in, const int* in_sizes, int n_in,
                              void* d_out, int out_size, void* d_ws, size_t ws_size,
                              hipStream_t stream){
    const float* in1  = (const float*)d_in[0];
    const float* in2  = (const float*)d_in[1];
    const float* w_in = (const float*)d_in[2];
    const float* b_in = (const float*)d_in[3];
    const float* w_v  = (const float*)d_in[4];
    const float* b_v  = (const float*)d_in[5];
    const float* scp  = (const float*)d_in[6];
    const float* pos1 = (const float*)d_in[7];
    const float* pos2 = (const float*)d_in[8];
    float* out = (float*)d_out;
    char* ws  = (char*)d_ws;

    const size_t PBYTES = (size_t)8*4096*512*2;   // 33.55 MB per bf16 (b,n,c) buffer
    unsigned short* p1t  = (unsigned short*)ws;                 // qfoc in-place after k_rows
    unsigned short* p2t  = (unsigned short*)(ws + PBYTES);      // pooled projected input2 == v
    unsigned short* kfoc = (unsigned short*)(ws + 2*PBYTES);    // focused k; reused as attn (b,c,n)
    float*          kvb  = (float*)(ws + 3*PBYTES);             // 512 KB
    unsigned*       wbf  = (unsigned*)(ws + 3*PBYTES + (size_t)8*16*32*32*4);  // 256 KB bf16 w_in

    hipMemsetAsync(kvb, 0, (size_t)8*16*32*32*sizeof(float), stream);
    k_wprep   <<<64,            256, 0, stream>>>(w_in, wbf);
    k_stage1  <<<12288,         256, 0, stream>>>(in1, in2, wbf, b_in, (unsigned*)p1t, p2t);
    k_rows    <<<dim3(2048,8),  256, 0, stream>>>((unsigned*)p1t, (const unsigned*)p2t, pos1, pos2, scp, (unsigned*)kfoc);
    k_kv      <<<dim3(8,16,8),  256, 0, stream>>>((const unsigned*)kfoc, (const unsigned*)p2t, kvb);
    k_attn    <<<dim3(64,16,8), 256, 0, stream>>>((const unsigned*)p1t, (const unsigned*)p2t, kvb, w_v, b_v, kfoc);
    k_up      <<<dim3(4,4096),  256, 0, stream>>>((const unsigned*)kfoc, out);
}